// Round 1
// baseline (90.635 us; speedup 1.0000x reference)
//
#include <hip/hip_runtime.h>

// ScatteringMapping closed form:
//   out[t, r, c] = sum over (i0,i1,i2) with
//       t = s1[i0]+s2[i1]+s3[i2] + mL[r] + mR[c]
//   of U3[r,i2]*U2[i2,i1]*U1[i1,i0]*U0[i0,c] * g^(s1[i0]+s2[i1]+s3[i2])
// where s_k = shifts[k-1], g = GAIN_PER_SAMPLE = 0.9999.
// One block per (i0,i1,i2) combo writes its 32x32 tap tile (4 KB contiguous).

#define NN 32
#define LN_G -1.0000500033334732e-4f  // ln(0.9999)

__global__ __launch_bounds__(256) void scatter_taps_kernel(
    const float* __restrict__ U,       // (4,32,32)
    const int*   __restrict__ shifts,  // (3,32)
    const int*   __restrict__ mL,      // (32,)
    const int*   __restrict__ mR,      // (32,)
    float*       __restrict__ out,     // (T,32,32)
    int T)
{
    const int combo = blockIdx.x;
    const int i0 = combo & 31;
    const int i1 = (combo >> 5) & 31;
    const int i2 = (combo >> 10) & 31;

    const int s1 = shifts[i0];
    const int s2 = shifts[NN + i1];
    const int s3 = shifts[2 * NN + i2];
    const int tbase = s1 + s2 + s3;

    // gain g^(s1+s2+s3); stage gains fold into one exponent
    const float gain = expf((float)tbase * LN_G);
    const float c12 = U[1 * NN * NN + i1 * NN + i0]   // U1[i1,i0]
                    * U[2 * NN * NN + i2 * NN + i1]   // U2[i2,i1]
                    * gain;

    const int tid = threadIdx.x;
#pragma unroll
    for (int e = 0; e < 4; ++e) {
        const int id = e * 256 + tid;     // 0..1023 == r*32+c
        const int r = id >> 5;
        const int c = id & 31;
        const float val = c12
                        * U[3 * NN * NN + r * NN + i2]   // U3[r,i2]
                        * U[i0 * NN + c];                // U0[i0,c]
        const int t = tbase + mL[r] + mR[c];
        if (t < T) {
            out[(size_t)t * (NN * NN) + id] = val;
        }
    }
}

extern "C" void kernel_launch(void* const* d_in, const int* in_sizes, int n_in,
                              void* d_out, int out_size, void* d_ws, size_t ws_size,
                              hipStream_t stream) {
    const float* U      = (const float*)d_in[0];  // (4,32,32) float32
    const int*   shifts = (const int*)d_in[1];    // (3,32) int32
    const int*   mL     = (const int*)d_in[2];    // (32,) int32
    const int*   mR     = (const int*)d_in[3];    // (32,) int32
    float* out = (float*)d_out;

    const int T = out_size / (NN * NN);

    // Zero the full output (poisoned 0xAA by harness; zeros are semantically
    // required for non-tap time slots).
    hipMemsetAsync(d_out, 0, (size_t)out_size * sizeof(float), stream);

    // One block per (i0,i1,i2) combo: 32^3 = 32768 blocks.
    scatter_taps_kernel<<<dim3(32 * 32 * 32), dim3(256), 0, stream>>>(
        U, shifts, mL, mR, out, T);
}